// Round 7
// baseline (2329.703 us; speedup 1.0000x reference)
//
#include <hip/hip_runtime.h>
#include <stdint.h>

#pragma clang fp contract(off)

#define BATCH 16
#define CCH   512
#define NLEN  1024
#define NH    8
#define DH    64

// ================= numpy-pairwise emulation (f32, no contraction) =================
__device__ float pw128(const float* __restrict__ x) {
    float r0=x[0],r1=x[1],r2=x[2],r3=x[3],r4=x[4],r5=x[5],r6=x[6],r7=x[7];
    for (int i = 8; i < 128; i += 8) {
        r0 += x[i+0]; r1 += x[i+1]; r2 += x[i+2]; r3 += x[i+3];
        r4 += x[i+4]; r5 += x[i+5]; r6 += x[i+6]; r7 += x[i+7];
    }
    return ((r0+r1)+(r2+r3))+((r4+r5)+(r6+r7));
}
__device__ float pw128_sqdev(const float* __restrict__ x, float m) {
    float r0,r1,r2,r3,r4,r5,r6,r7;
    {
        float d;
        d = x[0]-m; r0 = d*d;  d = x[1]-m; r1 = d*d;
        d = x[2]-m; r2 = d*d;  d = x[3]-m; r3 = d*d;
        d = x[4]-m; r4 = d*d;  d = x[5]-m; r5 = d*d;
        d = x[6]-m; r6 = d*d;  d = x[7]-m; r7 = d*d;
    }
    for (int i = 8; i < 128; i += 8) {
        float d;
        d = x[i+0]-m; r0 += d*d;  d = x[i+1]-m; r1 += d*d;
        d = x[i+2]-m; r2 += d*d;  d = x[i+3]-m; r3 += d*d;
        d = x[i+4]-m; r4 += d*d;  d = x[i+5]-m; r5 += d*d;
        d = x[i+6]-m; r6 += d*d;  d = x[i+7]-m; r7 += d*d;
    }
    return ((r0+r1)+(r2+r3))+((r4+r5)+(r6+r7));
}

// BN stats, numpy semantics (bit-exact): pairwise mean, two-pass var, CR f32 rsqrt.
__global__ __launch_bounds__(64) void bn_stats_np_k(const float* __restrict__ Y, int O,
                                                    float2* __restrict__ st)
{
    const int o = blockIdx.x;
    const int t = threadIdx.x;
    __shared__ float part[16];
    __shared__ float msh;
    if (t < 16) {
        const float* p = Y + ((size_t)t * O + o) * NLEN;
        float b0 = pw128(p), b1 = pw128(p+128), b2 = pw128(p+256), b3 = pw128(p+384);
        float b4 = pw128(p+512), b5 = pw128(p+640), b6 = pw128(p+768), b7 = pw128(p+896);
        part[t] = ((b0+b1)+(b2+b3))+((b4+b5)+(b6+b7));
    }
    __syncthreads();
    if (t == 0) {
        float s = part[0];
        for (int b = 1; b < 16; ++b) s += part[b];
        msh = s / 16384.0f;
    }
    __syncthreads();
    const float m = msh;
    if (t < 16) {
        const float* p = Y + ((size_t)t * O + o) * NLEN;
        float b0 = pw128_sqdev(p,     m), b1 = pw128_sqdev(p+128, m);
        float b2 = pw128_sqdev(p+256, m), b3 = pw128_sqdev(p+384, m);
        float b4 = pw128_sqdev(p+512, m), b5 = pw128_sqdev(p+640, m);
        float b6 = pw128_sqdev(p+768, m), b7 = pw128_sqdev(p+896, m);
        part[t] = ((b0+b1)+(b2+b3))+((b4+b5)+(b6+b7));
    }
    __syncthreads();
    if (t == 0) {
        float s = part[0];
        for (int b = 1; b < 16; ++b) s += part[b];
        float var = s / 16384.0f;
        float ve  = var + 1e-5f;
        float sq  = (float)sqrt((double)ve);    // correctly-rounded f32 sqrt
        float r   = (float)(1.0 / (double)sq);  // correctly-rounded f32 reciprocal
        st[o] = make_float2(m, r);
    }
}

// spike of bn output, f32 reference op order
__device__ inline bool spike_f32(float y, float2 s, float g, float b) {
    float t1 = y - s.x;
    float t2 = t1 * s.y;
    float t3 = t2 * g;
    float t4 = t3 + b;
    float u  = t4 / 2.0f - 1.0f;
    return u >= 0.0f;
}

// ================= GEMM v3: 128x128 tile, 256 threads, 8x8 micro, BK=32, prefetch =================
// Bit-exactness invariant: each output element is one thread's strict sequential
// ascending-c f32 FMA chain (matches np einsum), bias added once at the end.
// Per-lane LDS traffic = 1.0 B/FMA (8x8) -> under the ~112 B/cyc/CU LDS ceiling; a-reads
// are 4-address wave broadcasts.
// MODE 0: X = Xf (f32)   MODE 1: X = u8 spikes   MODE 2: X = f32(Xf + Xs8)
template<int MODE>
__global__ __launch_bounds__(256, 3) void gemm_k(
    const float* __restrict__ W, const float* __restrict__ Xf, const uint8_t* __restrict__ Xs8,
    const float* __restrict__ bias, float* __restrict__ Y,
    int O, int Cin, int N)
{
    __shared__ float Ws[32][132];   // [k][o]
    __shared__ float Xs[32][132];   // [k][n]
    const int b = blockIdx.z;
    const size_t xbase = (size_t)b * Cin * N;
    float* Yb = Y + (size_t)b * O * N;
    const int o0 = blockIdx.y * 128;
    const int n0 = blockIdx.x * 128;
    const int t  = threadIdx.x;
    const int tx = t & 15;          // n: cols tx*4 and 64+tx*4
    const int ty = t >> 4;          // 0..15: o rows ty*8 .. ty*8+7

    // staging map: W-tile 32k x 128o, 16 floats/thread along k
    const int wr = t >> 1;          // 0..127  o-row
    const int wk = (t & 1) << 4;    // 0 or 16
    // X-tile 32k x 128n, 16 floats/thread (two k-rows of 8)
    const int xk = t >> 4;          // 0..15 (and +16)
    const int xc = (t & 15) << 3;   // 0..120

    float acc[8][8];
#pragma unroll
    for (int i = 0; i < 8; ++i)
#pragma unroll
        for (int j = 0; j < 8; ++j) acc[i][j] = 0.0f;

    float wbuf[16];
    float xbuf[16];

    auto loadG = [&](int k0) {
        const float* wp = W + (size_t)(o0 + wr) * Cin + k0 + wk;
#pragma unroll
        for (int q = 0; q < 4; ++q) {
            float4 w4 = *reinterpret_cast<const float4*>(wp + q * 4);
            wbuf[q*4+0]=w4.x; wbuf[q*4+1]=w4.y; wbuf[q*4+2]=w4.z; wbuf[q*4+3]=w4.w;
        }
#pragma unroll
        for (int h = 0; h < 2; ++h) {
            size_t off = xbase + (size_t)(k0 + xk + 16*h) * N + n0 + xc;
            if (MODE == 0) {
                float4 v0 = *reinterpret_cast<const float4*>(Xf + off);
                float4 v1 = *reinterpret_cast<const float4*>(Xf + off + 4);
                xbuf[8*h+0]=v0.x; xbuf[8*h+1]=v0.y; xbuf[8*h+2]=v0.z; xbuf[8*h+3]=v0.w;
                xbuf[8*h+4]=v1.x; xbuf[8*h+5]=v1.y; xbuf[8*h+6]=v1.z; xbuf[8*h+7]=v1.w;
            } else if (MODE == 1) {
                uchar4 u0 = *reinterpret_cast<const uchar4*>(Xs8 + off);
                uchar4 u1 = *reinterpret_cast<const uchar4*>(Xs8 + off + 4);
                xbuf[8*h+0]=(float)u0.x; xbuf[8*h+1]=(float)u0.y;
                xbuf[8*h+2]=(float)u0.z; xbuf[8*h+3]=(float)u0.w;
                xbuf[8*h+4]=(float)u1.x; xbuf[8*h+5]=(float)u1.y;
                xbuf[8*h+6]=(float)u1.z; xbuf[8*h+7]=(float)u1.w;
            } else {
                float4 v0 = *reinterpret_cast<const float4*>(Xf + off);
                float4 v1 = *reinterpret_cast<const float4*>(Xf + off + 4);
                uchar4 u0 = *reinterpret_cast<const uchar4*>(Xs8 + off);
                uchar4 u1 = *reinterpret_cast<const uchar4*>(Xs8 + off + 4);
                xbuf[8*h+0]=v0.x+(float)u0.x; xbuf[8*h+1]=v0.y+(float)u0.y;
                xbuf[8*h+2]=v0.z+(float)u0.z; xbuf[8*h+3]=v0.w+(float)u0.w;
                xbuf[8*h+4]=v1.x+(float)u1.x; xbuf[8*h+5]=v1.y+(float)u1.y;
                xbuf[8*h+6]=v1.z+(float)u1.z; xbuf[8*h+7]=v1.w+(float)u1.w;
            }
        }
    };
    auto stage = [&]() {
#pragma unroll
        for (int q = 0; q < 16; ++q) Ws[wk + q][wr] = wbuf[q];
        *reinterpret_cast<float4*>(&Xs[xk][xc])          = make_float4(xbuf[0],xbuf[1],xbuf[2],xbuf[3]);
        *reinterpret_cast<float4*>(&Xs[xk][xc + 4])      = make_float4(xbuf[4],xbuf[5],xbuf[6],xbuf[7]);
        *reinterpret_cast<float4*>(&Xs[xk + 16][xc])     = make_float4(xbuf[8],xbuf[9],xbuf[10],xbuf[11]);
        *reinterpret_cast<float4*>(&Xs[xk + 16][xc + 4]) = make_float4(xbuf[12],xbuf[13],xbuf[14],xbuf[15]);
    };

    loadG(0);
    stage();
    __syncthreads();
    for (int k0 = 0;;) {
        const int kn = k0 + 32;
        const bool more = kn < Cin;
        if (more) loadG(kn);
#pragma unroll
        for (int kk = 0; kk < 32; ++kk) {
            float4 a0 = *reinterpret_cast<const float4*>(&Ws[kk][ty * 8]);
            float4 a1 = *reinterpret_cast<const float4*>(&Ws[kk][ty * 8 + 4]);
            float4 b0 = *reinterpret_cast<const float4*>(&Xs[kk][tx * 4]);
            float4 b1 = *reinterpret_cast<const float4*>(&Xs[kk][64 + tx * 4]);
            float av[8] = {a0.x, a0.y, a0.z, a0.w, a1.x, a1.y, a1.z, a1.w};
            float bv[8] = {b0.x, b0.y, b0.z, b0.w, b1.x, b1.y, b1.z, b1.w};
#pragma unroll
            for (int i = 0; i < 8; ++i)
#pragma unroll
                for (int j = 0; j < 8; ++j)
                    acc[i][j] = fmaf(av[i], bv[j], acc[i][j]);   // strict sequential-c chain
        }
        if (!more) break;
        __syncthreads();
        stage();
        __syncthreads();
        k0 = kn;
    }
#pragma unroll
    for (int i = 0; i < 8; ++i) {
        const int o = o0 + ty * 8 + i;
        const float bb = bias ? bias[o] : 0.0f;
        float* yp = Yb + (size_t)o * N + n0;
        float4 r0, r1;
        r0.x = acc[i][0] + bb; r0.y = acc[i][1] + bb;
        r0.z = acc[i][2] + bb; r0.w = acc[i][3] + bb;
        r1.x = acc[i][4] + bb; r1.y = acc[i][5] + bb;
        r1.z = acc[i][6] + bb; r1.w = acc[i][7] + bb;
        *reinterpret_cast<float4*>(yp + tx * 4)      = r0;
        *reinterpret_cast<float4*>(yp + 64 + tx * 4) = r1;
    }
}

// ================= spike + transpose to [B,H,N,D] u8 =================
__global__ __launch_bounds__(256) void spike_pack_k(
    const float* __restrict__ Y, const float2* __restrict__ st,
    const float* __restrict__ g, const float* __restrict__ bet,
    uint8_t* __restrict__ out)
{
    const int nt = blockIdx.x, h = blockIdx.y, b = blockIdx.z;
    __shared__ uint8_t tile[64][68];
    const int t = threadIdx.x;
    {
        const int i = t & 63, dq = t >> 6;
#pragma unroll
        for (int p = 0; p < 16; ++p) {
            int d = dq * 16 + p;
            int c = h * 64 + d;
            float y = Y[((size_t)b * CCH + c) * NLEN + nt * 64 + i];
            tile[d][i] = spike_f32(y, st[c], g[c], bet[c]) ? 1 : 0;
        }
    }
    __syncthreads();
    {
        const int d = t & 63, iq = t >> 6;
#pragma unroll
        for (int p = 0; p < 16; ++p) {
            int i = iq * 16 + p;
            out[((size_t)(b * NH + h) * NLEN + nt * 64 + i) * DH + d] = tile[d][i];
        }
    }
}

// ================= M = K^T V  [B*H, 64, 64]  (exact integers) =================
__global__ __launch_bounds__(256) void ktv_k(const uint8_t* __restrict__ Kb, const uint8_t* __restrict__ Vb,
                                             float* __restrict__ M)
{
    const int bh = blockIdx.x;
    const uint8_t* kp = Kb + (size_t)bh * NLEN * DH;
    const uint8_t* vp = Vb + (size_t)bh * NLEN * DH;
    __shared__ float ks[64][68];
    __shared__ float vs[64][68];
    const int t = threadIdx.x;
    const int d2 = t & 63, g4 = t >> 6;
    float acc[16];
#pragma unroll
    for (int j = 0; j < 16; ++j) acc[j] = 0.f;

    for (int nc = 0; nc < NLEN; nc += 64) {
#pragma unroll
        for (int p = 0; p < 16; ++p) {
            int idx = t + p * 256;
            int r = idx >> 6, d = idx & 63;
            ks[r][d] = (float)kp[(size_t)(nc + r) * DH + d];
            vs[r][d] = (float)vp[(size_t)(nc + r) * DH + d];
        }
        __syncthreads();
        for (int n = 0; n < 64; ++n) {
            float vv = vs[n][d2];
#pragma unroll
            for (int j = 0; j < 16; ++j)
                acc[j] += ks[n][g4 * 16 + j] * vv;
        }
        __syncthreads();
    }
#pragma unroll
    for (int j = 0; j < 16; ++j)
        M[(size_t)bh * 4096 + (size_t)(g4 * 16 + j) * 64 + d2] = acc[j];
}

// ================= attn = Q @ M, integer spike attn>=8, write [B,C,N] u8 =================
__global__ __launch_bounds__(256) void attn_spike_k(const uint8_t* __restrict__ Qb, const float* __restrict__ M,
                                                    uint8_t* __restrict__ A)
{
    const int nt = blockIdx.x, h = blockIdx.y, b = blockIdx.z;
    const int bh = b * NH + h;
    __shared__ float Ms[64][68];
    __shared__ float qs[64][65];
    const int t = threadIdx.x;
#pragma unroll
    for (int p = 0; p < 16; ++p) {
        int idx = t + p * 256;
        int r = idx >> 6, c = idx & 63;
        Ms[r][c] = M[(size_t)bh * 4096 + idx];
        qs[c][r] = (float)Qb[((size_t)bh * NLEN + nt * 64 + r) * DH + c];
    }
    __syncthreads();
    const int n = t & 63, dg = t >> 6;
    float acc[16];
#pragma unroll
    for (int j = 0; j < 16; ++j) acc[j] = 0.f;
    for (int d1 = 0; d1 < 64; ++d1) {
        float qv = qs[d1][n];
#pragma unroll
        for (int j = 0; j < 16; ++j)
            acc[j] += qv * Ms[d1][dg * 16 + j];
    }
#pragma unroll
    for (int j = 0; j < 16; ++j) {
        int d = dg * 16 + j;
        A[((size_t)b * CCH + h * 64 + d) * NLEN + nt * 64 + n] = (acc[j] >= 8.0f) ? 1 : 0;
    }
}

// ================= spike -> u8 store at channel offset =================
__global__ __launch_bounds__(256) void spike_store_k(
    const float* __restrict__ Y, const float2* __restrict__ st,
    const float* __restrict__ g, const float* __restrict__ bet,
    uint8_t* __restrict__ H, int Oc, int o_off, int Otot)
{
    size_t i4 = (size_t)blockIdx.x * 256 + threadIdx.x;
    size_t total = (size_t)BATCH * Oc * (NLEN / 4);
    if (i4 >= total) return;
    int n4 = (int)(i4 & 255);
    int o  = (int)((i4 >> 8) % Oc);
    int b  = (int)(i4 / ((size_t)256 * Oc));
    float4 y = reinterpret_cast<const float4*>(Y)[i4];
    float2 s = st[o];
    float gg = g[o], bb = bet[o];
    uchar4 r;
    r.x = spike_f32(y.x, s, gg, bb) ? 1 : 0;
    r.y = spike_f32(y.y, s, gg, bb) ? 1 : 0;
    r.z = spike_f32(y.z, s, gg, bb) ? 1 : 0;
    r.w = spike_f32(y.w, s, gg, bb) ? 1 : 0;
    *reinterpret_cast<uchar4*>(H + ((size_t)(b * Otot + o_off + o)) * NLEN + n4 * 4) = r;
}

// ================= out = (x + ares) + spike(bn(Y)) in np f32 order =================
__global__ __launch_bounds__(256) void final_k(
    const float* __restrict__ Y, const float2* __restrict__ st,
    const float* __restrict__ g, const float* __restrict__ bet,
    const float* __restrict__ x, const uint8_t* __restrict__ ares,
    float* __restrict__ Out)
{
    size_t i4 = (size_t)blockIdx.x * 256 + threadIdx.x;
    size_t total = (size_t)BATCH * CCH * (NLEN / 4);
    if (i4 >= total) return;
    int o = (int)((i4 >> 8) % CCH);
    float4 y  = reinterpret_cast<const float4*>(Y)[i4];
    float4 xv = reinterpret_cast<const float4*>(x)[i4];
    uchar4 av = reinterpret_cast<const uchar4*>(ares)[i4];
    float2 s = st[o];
    float gg = g[o], bb = bet[o];
    float4 r;
    {
        float x1;
        x1 = xv.x + (float)av.x; r.x = x1 + (spike_f32(y.x, s, gg, bb) ? 1.0f : 0.0f);
        x1 = xv.y + (float)av.y; r.y = x1 + (spike_f32(y.y, s, gg, bb) ? 1.0f : 0.0f);
        x1 = xv.z + (float)av.z; r.z = x1 + (spike_f32(y.z, s, gg, bb) ? 1.0f : 0.0f);
        x1 = xv.w + (float)av.w; r.w = x1 + (spike_f32(y.w, s, gg, bb) ? 1.0f : 0.0f);
    }
    reinterpret_cast<float4*>(Out)[i4] = r;
}

extern "C" void kernel_launch(void* const* d_in, const int* in_sizes, int n_in,
                              void* d_out, int out_size, void* d_ws, size_t ws_size,
                              hipStream_t stream)
{
    const float* x         = (const float*)d_in[0];
    const float* q_w       = (const float*)d_in[1];
    const float* q_g       = (const float*)d_in[2];
    const float* q_b       = (const float*)d_in[3];
    const float* k_w       = (const float*)d_in[4];
    const float* k_g       = (const float*)d_in[5];
    const float* k_b       = (const float*)d_in[6];
    const float* v_w       = (const float*)d_in[7];
    const float* v_g       = (const float*)d_in[8];
    const float* v_b       = (const float*)d_in[9];
    const float* proj_w    = (const float*)d_in[10];
    const float* proj_bias = (const float*)d_in[11];
    const float* proj_g    = (const float*)d_in[12];
    const float* proj_b    = (const float*)d_in[13];
    const float* fc1_w     = (const float*)d_in[14];
    const float* fc1_bias  = (const float*)d_in[15];
    const float* fc1_g     = (const float*)d_in[16];
    const float* fc1_b     = (const float*)d_in[17];
    const float* fc2_w     = (const float*)d_in[18];
    const float* fc2_bias  = (const float*)d_in[19];
    const float* fc2_g     = (const float*)d_in[20];
    const float* fc2_b     = (const float*)d_in[21];
    float* out = (float*)d_out;

    char* ws = (char*)d_ws;
    const size_t MiB = 1ull << 20;
    if (ws_size < 115 * MiB) return;

    // ---- layout (115 MiB) ----
    float*    Af    = (float*)(ws);                  // 64 MiB: f32 GEMM out (up to 1024 ch for fc1 chunks)
    uint8_t*  ab    = (uint8_t*)(ws + 64 * MiB);     //  8 MiB: attention spikes [B,C,N]
    uint8_t*  ares  = (uint8_t*)(ws + 72 * MiB);     //  8 MiB: proj spikes, live to end
    uint8_t*  qb    = (uint8_t*)(ws + 80 * MiB);     //  8 MiB [B,H,N,D]
    uint8_t*  kb    = (uint8_t*)(ws + 88 * MiB);     //  8 MiB
    uint8_t*  vb    = (uint8_t*)(ws + 96 * MiB);     //  8 MiB
    uint8_t*  hb    = (uint8_t*)(ws + 80 * MiB);     // 32 MiB: fc1 spikes (overlays q/k/v after attn)
    float*    Mbuf  = (float*)(ws + 112 * MiB);      //  2 MiB
    float2*   stats = (float2*)(ws + 114 * MiB);     // 16 KiB

    dim3 thr256(256);

    // --- q, k, v ---
    const float* Wt[3] = {q_w, k_w, v_w};
    const float* Gt[3] = {q_g, k_g, v_g};
    const float* Bt[3] = {q_b, k_b, v_b};
    uint8_t*     Pt[3] = {qb, kb, vb};
    for (int tsr = 0; tsr < 3; ++tsr) {
        gemm_k<0><<<dim3(8, 4, 16), thr256, 0, stream>>>(Wt[tsr], x, nullptr, nullptr, Af, 512, 512, 1024);
        bn_stats_np_k<<<dim3(512), dim3(64), 0, stream>>>(Af, 512, stats);
        spike_pack_k<<<dim3(16, 8, 16), thr256, 0, stream>>>(Af, stats, Gt[tsr], Bt[tsr], Pt[tsr]);
    }

    // --- attention (exact integers) ---
    ktv_k<<<dim3(128), thr256, 0, stream>>>(kb, vb, Mbuf);
    attn_spike_k<<<dim3(16, 8, 16), thr256, 0, stream>>>(qb, Mbuf, ab);

    // --- proj ---
    gemm_k<1><<<dim3(8, 4, 16), thr256, 0, stream>>>(proj_w, nullptr, ab, proj_bias, Af, 512, 512, 1024);
    bn_stats_np_k<<<dim3(512), dim3(64), 0, stream>>>(Af, 512, stats);
    spike_store_k<<<dim3(8192), thr256, 0, stream>>>(Af, stats, proj_g, proj_b, ares, 512, 0, 512);

    // --- fc1 on x1 = f32(x + ares), 2 chunks of 1024 out-ch ---
    for (int ch = 0; ch < 2; ++ch) {
        gemm_k<2><<<dim3(8, 8, 16), thr256, 0, stream>>>(fc1_w + (size_t)ch * 1024 * 512, x, ares,
                                                         fc1_bias + ch * 1024, Af, 1024, 512, 1024);
        bn_stats_np_k<<<dim3(1024), dim3(64), 0, stream>>>(Af, 1024, stats);
        spike_store_k<<<dim3(16384), thr256, 0, stream>>>(Af, stats, fc1_g + ch * 1024, fc1_b + ch * 1024,
                                                          hb, 1024, ch * 1024, 2048);
    }

    // --- fc2 + final residual ---
    gemm_k<1><<<dim3(8, 4, 16), thr256, 0, stream>>>(fc2_w, nullptr, hb, fc2_bias, Af, 512, 2048, 1024);
    bn_stats_np_k<<<dim3(512), dim3(64), 0, stream>>>(Af, 512, stats);
    final_k<<<dim3(8192), thr256, 0, stream>>>(Af, stats, fc2_g, fc2_b, x, ares, out);
}

// Round 8
// 1820.619 us; speedup vs baseline: 1.2796x; 1.2796x over previous
//
#include <hip/hip_runtime.h>
#include <stdint.h>

#pragma clang fp contract(off)

#define BATCH 16
#define CCH   512
#define NLEN  1024
#define NH    8
#define DH    64

// ================= numpy-pairwise emulation (f32, no contraction) =================
__device__ float pw128(const float* __restrict__ x) {
    float r0=x[0],r1=x[1],r2=x[2],r3=x[3],r4=x[4],r5=x[5],r6=x[6],r7=x[7];
    for (int i = 8; i < 128; i += 8) {
        r0 += x[i+0]; r1 += x[i+1]; r2 += x[i+2]; r3 += x[i+3];
        r4 += x[i+4]; r5 += x[i+5]; r6 += x[i+6]; r7 += x[i+7];
    }
    return ((r0+r1)+(r2+r3))+((r4+r5)+(r6+r7));
}
__device__ float pw128_sqdev(const float* __restrict__ x, float m) {
    float r0,r1,r2,r3,r4,r5,r6,r7;
    {
        float d;
        d = x[0]-m; r0 = d*d;  d = x[1]-m; r1 = d*d;
        d = x[2]-m; r2 = d*d;  d = x[3]-m; r3 = d*d;
        d = x[4]-m; r4 = d*d;  d = x[5]-m; r5 = d*d;
        d = x[6]-m; r6 = d*d;  d = x[7]-m; r7 = d*d;
    }
    for (int i = 8; i < 128; i += 8) {
        float d;
        d = x[i+0]-m; r0 += d*d;  d = x[i+1]-m; r1 += d*d;
        d = x[i+2]-m; r2 += d*d;  d = x[i+3]-m; r3 += d*d;
        d = x[i+4]-m; r4 += d*d;  d = x[i+5]-m; r5 += d*d;
        d = x[i+6]-m; r6 += d*d;  d = x[i+7]-m; r7 += d*d;
    }
    return ((r0+r1)+(r2+r3))+((r4+r5)+(r6+r7));
}

// BN stats, numpy semantics (bit-exact): pairwise mean, two-pass var, CR f32 rsqrt.
__global__ __launch_bounds__(64) void bn_stats_np_k(const float* __restrict__ Y, int O,
                                                    float2* __restrict__ st)
{
    const int o = blockIdx.x;
    const int t = threadIdx.x;
    __shared__ float part[16];
    __shared__ float msh;
    if (t < 16) {
        const float* p = Y + ((size_t)t * O + o) * NLEN;
        float b0 = pw128(p), b1 = pw128(p+128), b2 = pw128(p+256), b3 = pw128(p+384);
        float b4 = pw128(p+512), b5 = pw128(p+640), b6 = pw128(p+768), b7 = pw128(p+896);
        part[t] = ((b0+b1)+(b2+b3))+((b4+b5)+(b6+b7));
    }
    __syncthreads();
    if (t == 0) {
        float s = part[0];
        for (int b = 1; b < 16; ++b) s += part[b];
        msh = s / 16384.0f;
    }
    __syncthreads();
    const float m = msh;
    if (t < 16) {
        const float* p = Y + ((size_t)t * O + o) * NLEN;
        float b0 = pw128_sqdev(p,     m), b1 = pw128_sqdev(p+128, m);
        float b2 = pw128_sqdev(p+256, m), b3 = pw128_sqdev(p+384, m);
        float b4 = pw128_sqdev(p+512, m), b5 = pw128_sqdev(p+640, m);
        float b6 = pw128_sqdev(p+768, m), b7 = pw128_sqdev(p+896, m);
        part[t] = ((b0+b1)+(b2+b3))+((b4+b5)+(b6+b7));
    }
    __syncthreads();
    if (t == 0) {
        float s = part[0];
        for (int b = 1; b < 16; ++b) s += part[b];
        float var = s / 16384.0f;
        float ve  = var + 1e-5f;
        float sq  = (float)sqrt((double)ve);    // correctly-rounded f32 sqrt
        float r   = (float)(1.0 / (double)sq);  // correctly-rounded f32 reciprocal
        st[o] = make_float2(m, r);
    }
}

// spike of bn output, f32 reference op order
__device__ inline bool spike_f32(float y, float2 s, float g, float b) {
    float t1 = y - s.x;
    float t2 = t1 * s.y;
    float t3 = t2 * g;
    float t4 = t3 + b;
    float u  = t4 / 2.0f - 1.0f;
    return u >= 0.0f;
}

// ================= GEMM v4: 32o x 256n tile, 256 thr, micro 8o x 4n, BK=16 =================
// Wave-uniform W broadcast: wave w owns o-rows [w*8, w*8+8) -> its 2 a-reads are
// same-address broadcasts (near-free on the LDS pipe); only the X read (1 b128,
// lane-distinct) pays full cost. acc = 32 regs (no spill cliff).
// Bit-exactness invariant: each output element is one thread's strict sequential
// ascending-c f32 FMA chain (matches np einsum); bias added once at the end.
// MODE 0: X = Xf (f32)   MODE 1: X = u8 spikes   MODE 2: X = f32(Xf + Xs8)
template<int MODE>
__global__ __launch_bounds__(256, 2) void gemm_k(
    const float* __restrict__ W, const float* __restrict__ Xf, const uint8_t* __restrict__ Xs8,
    const float* __restrict__ bias, float* __restrict__ Y,
    int O, int Cin, int N)
{
    __shared__ float Ws[16][36];    // [k][o], row = 144 B (16B-aligned)
    __shared__ float Xs[16][260];   // [k][n], row = 1040 B (16B-aligned)
    const int b = blockIdx.z;
    const size_t xbase = (size_t)b * Cin * N;
    float* Yb = Y + (size_t)b * O * N;
    const int o0 = blockIdx.y * 32;
    const int n0 = blockIdx.x * 256;
    const int t    = threadIdx.x;
    const int w8   = (t >> 6) << 3;   // wave's o-offset: 0,8,16,24 (wave-uniform)
    const int lane = t & 63;

    // staging maps
    const int wor = t >> 3;           // 0..31  W o-row
    const int wok = (t & 7) * 2;      // 0..14  W k-offset (float2)
    const int xr  = t >> 5;           // 0..7   X k-row (and +8)
    const int xc  = (t & 31) * 8;     // 0..248 X n-offset

    float acc[8][4];
#pragma unroll
    for (int i = 0; i < 8; ++i)
#pragma unroll
        for (int j = 0; j < 4; ++j) acc[i][j] = 0.0f;

    float  wb0, wb1;
    float  xbuf[16];

    auto loadG = [&](int k0) {
        const float* wp = W + (size_t)(o0 + wor) * Cin + k0 + wok;
        float2 w2 = *reinterpret_cast<const float2*>(wp);
        wb0 = w2.x; wb1 = w2.y;
#pragma unroll
        for (int g = 0; g < 2; ++g) {
            size_t off = xbase + (size_t)(k0 + xr + 8 * g) * N + n0 + xc;
            if (MODE == 0) {
                float4 v0 = *reinterpret_cast<const float4*>(Xf + off);
                float4 v1 = *reinterpret_cast<const float4*>(Xf + off + 4);
                xbuf[g*8+0]=v0.x; xbuf[g*8+1]=v0.y; xbuf[g*8+2]=v0.z; xbuf[g*8+3]=v0.w;
                xbuf[g*8+4]=v1.x; xbuf[g*8+5]=v1.y; xbuf[g*8+6]=v1.z; xbuf[g*8+7]=v1.w;
            } else if (MODE == 1) {
                uchar4 u0 = *reinterpret_cast<const uchar4*>(Xs8 + off);
                uchar4 u1 = *reinterpret_cast<const uchar4*>(Xs8 + off + 4);
                xbuf[g*8+0]=(float)u0.x; xbuf[g*8+1]=(float)u0.y;
                xbuf[g*8+2]=(float)u0.z; xbuf[g*8+3]=(float)u0.w;
                xbuf[g*8+4]=(float)u1.x; xbuf[g*8+5]=(float)u1.y;
                xbuf[g*8+6]=(float)u1.z; xbuf[g*8+7]=(float)u1.w;
            } else {
                float4 v0 = *reinterpret_cast<const float4*>(Xf + off);
                float4 v1 = *reinterpret_cast<const float4*>(Xf + off + 4);
                uchar4 u0 = *reinterpret_cast<const uchar4*>(Xs8 + off);
                uchar4 u1 = *reinterpret_cast<const uchar4*>(Xs8 + off + 4);
                xbuf[g*8+0]=v0.x+(float)u0.x; xbuf[g*8+1]=v0.y+(float)u0.y;
                xbuf[g*8+2]=v0.z+(float)u0.z; xbuf[g*8+3]=v0.w+(float)u0.w;
                xbuf[g*8+4]=v1.x+(float)u1.x; xbuf[g*8+5]=v1.y+(float)u1.y;
                xbuf[g*8+6]=v1.z+(float)u1.z; xbuf[g*8+7]=v1.w+(float)u1.w;
            }
        }
    };
    auto stage = [&]() {
        Ws[wok][wor]     = wb0;
        Ws[wok + 1][wor] = wb1;
#pragma unroll
        for (int g = 0; g < 2; ++g) {
            *reinterpret_cast<float4*>(&Xs[xr + 8*g][xc])     = make_float4(xbuf[g*8+0],xbuf[g*8+1],xbuf[g*8+2],xbuf[g*8+3]);
            *reinterpret_cast<float4*>(&Xs[xr + 8*g][xc + 4]) = make_float4(xbuf[g*8+4],xbuf[g*8+5],xbuf[g*8+6],xbuf[g*8+7]);
        }
    };

    loadG(0);
    stage();
    __syncthreads();
    for (int k0 = 0;;) {
        const int kn = k0 + 16;
        const bool more = kn < Cin;
        if (more) loadG(kn);
#pragma unroll
        for (int kk = 0; kk < 16; ++kk) {
            float4 a0 = *reinterpret_cast<const float4*>(&Ws[kk][w8]);       // broadcast
            float4 a1 = *reinterpret_cast<const float4*>(&Ws[kk][w8 + 4]);   // broadcast
            float4 bb = *reinterpret_cast<const float4*>(&Xs[kk][lane * 4]); // distinct
            float av[8] = {a0.x, a0.y, a0.z, a0.w, a1.x, a1.y, a1.z, a1.w};
            float bv[4] = {bb.x, bb.y, bb.z, bb.w};
#pragma unroll
            for (int i = 0; i < 8; ++i)
#pragma unroll
                for (int j = 0; j < 4; ++j)
                    acc[i][j] = fmaf(av[i], bv[j], acc[i][j]);   // strict sequential-c chain
        }
        if (!more) break;
        __syncthreads();
        stage();
        __syncthreads();
        k0 = kn;
    }
#pragma unroll
    for (int i = 0; i < 8; ++i) {
        const int o = o0 + w8 + i;
        const float bb = bias ? bias[o] : 0.0f;
        float4 r;
        r.x = acc[i][0] + bb; r.y = acc[i][1] + bb;
        r.z = acc[i][2] + bb; r.w = acc[i][3] + bb;
        *reinterpret_cast<float4*>(Yb + (size_t)o * N + n0 + lane * 4) = r;
    }
}

// ================= spike + transpose to [B,H,N,D] u8 =================
__global__ __launch_bounds__(256) void spike_pack_k(
    const float* __restrict__ Y, const float2* __restrict__ st,
    const float* __restrict__ g, const float* __restrict__ bet,
    uint8_t* __restrict__ out)
{
    const int nt = blockIdx.x, h = blockIdx.y, b = blockIdx.z;
    __shared__ uint8_t tile[64][68];
    const int t = threadIdx.x;
    {
        const int i = t & 63, dq = t >> 6;
#pragma unroll
        for (int p = 0; p < 16; ++p) {
            int d = dq * 16 + p;
            int c = h * 64 + d;
            float y = Y[((size_t)b * CCH + c) * NLEN + nt * 64 + i];
            tile[d][i] = spike_f32(y, st[c], g[c], bet[c]) ? 1 : 0;
        }
    }
    __syncthreads();
    {
        const int d = t & 63, iq = t >> 6;
#pragma unroll
        for (int p = 0; p < 16; ++p) {
            int i = iq * 16 + p;
            out[((size_t)(b * NH + h) * NLEN + nt * 64 + i) * DH + d] = tile[d][i];
        }
    }
}

// ================= M = K^T V  [B*H, 64, 64]  (exact integers) =================
__global__ __launch_bounds__(256) void ktv_k(const uint8_t* __restrict__ Kb, const uint8_t* __restrict__ Vb,
                                             float* __restrict__ M)
{
    const int bh = blockIdx.x;
    const uint8_t* kp = Kb + (size_t)bh * NLEN * DH;
    const uint8_t* vp = Vb + (size_t)bh * NLEN * DH;
    __shared__ float ks[64][68];
    __shared__ float vs[64][68];
    const int t = threadIdx.x;
    const int d2 = t & 63, g4 = t >> 6;
    float acc[16];
#pragma unroll
    for (int j = 0; j < 16; ++j) acc[j] = 0.f;

    for (int nc = 0; nc < NLEN; nc += 64) {
#pragma unroll
        for (int p = 0; p < 16; ++p) {
            int idx = t + p * 256;
            int r = idx >> 6, d = idx & 63;
            ks[r][d] = (float)kp[(size_t)(nc + r) * DH + d];
            vs[r][d] = (float)vp[(size_t)(nc + r) * DH + d];
        }
        __syncthreads();
        for (int n = 0; n < 64; ++n) {
            float vv = vs[n][d2];
#pragma unroll
            for (int j = 0; j < 16; ++j)
                acc[j] += ks[n][g4 * 16 + j] * vv;
        }
        __syncthreads();
    }
#pragma unroll
    for (int j = 0; j < 16; ++j)
        M[(size_t)bh * 4096 + (size_t)(g4 * 16 + j) * 64 + d2] = acc[j];
}

// ================= attn = Q @ M, integer spike attn>=8, write [B,C,N] u8 =================
__global__ __launch_bounds__(256) void attn_spike_k(const uint8_t* __restrict__ Qb, const float* __restrict__ M,
                                                    uint8_t* __restrict__ A)
{
    const int nt = blockIdx.x, h = blockIdx.y, b = blockIdx.z;
    const int bh = b * NH + h;
    __shared__ float Ms[64][68];
    __shared__ float qs[64][65];
    const int t = threadIdx.x;
#pragma unroll
    for (int p = 0; p < 16; ++p) {
        int idx = t + p * 256;
        int r = idx >> 6, c = idx & 63;
        Ms[r][c] = M[(size_t)bh * 4096 + idx];
        qs[c][r] = (float)Qb[((size_t)bh * NLEN + nt * 64 + r) * DH + c];
    }
    __syncthreads();
    const int n = t & 63, dg = t >> 6;
    float acc[16];
#pragma unroll
    for (int j = 0; j < 16; ++j) acc[j] = 0.f;
    for (int d1 = 0; d1 < 64; ++d1) {
        float qv = qs[d1][n];
#pragma unroll
        for (int j = 0; j < 16; ++j)
            acc[j] += qv * Ms[d1][dg * 16 + j];
    }
#pragma unroll
    for (int j = 0; j < 16; ++j) {
        int d = dg * 16 + j;
        A[((size_t)b * CCH + h * 64 + d) * NLEN + nt * 64 + n] = (acc[j] >= 8.0f) ? 1 : 0;
    }
}

// ================= spike -> u8 store at channel offset =================
__global__ __launch_bounds__(256) void spike_store_k(
    const float* __restrict__ Y, const float2* __restrict__ st,
    const float* __restrict__ g, const float* __restrict__ bet,
    uint8_t* __restrict__ H, int Oc, int o_off, int Otot)
{
    size_t i4 = (size_t)blockIdx.x * 256 + threadIdx.x;
    size_t total = (size_t)BATCH * Oc * (NLEN / 4);
    if (i4 >= total) return;
    int n4 = (int)(i4 & 255);
    int o  = (int)((i4 >> 8) % Oc);
    int b  = (int)(i4 / ((size_t)256 * Oc));
    float4 y = reinterpret_cast<const float4*>(Y)[i4];
    float2 s = st[o];
    float gg = g[o], bb = bet[o];
    uchar4 r;
    r.x = spike_f32(y.x, s, gg, bb) ? 1 : 0;
    r.y = spike_f32(y.y, s, gg, bb) ? 1 : 0;
    r.z = spike_f32(y.z, s, gg, bb) ? 1 : 0;
    r.w = spike_f32(y.w, s, gg, bb) ? 1 : 0;
    *reinterpret_cast<uchar4*>(H + ((size_t)(b * Otot + o_off + o)) * NLEN + n4 * 4) = r;
}

// ================= out = (x + ares) + spike(bn(Y)) in np f32 order =================
__global__ __launch_bounds__(256) void final_k(
    const float* __restrict__ Y, const float2* __restrict__ st,
    const float* __restrict__ g, const float* __restrict__ bet,
    const float* __restrict__ x, const uint8_t* __restrict__ ares,
    float* __restrict__ Out)
{
    size_t i4 = (size_t)blockIdx.x * 256 + threadIdx.x;
    size_t total = (size_t)BATCH * CCH * (NLEN / 4);
    if (i4 >= total) return;
    int o = (int)((i4 >> 8) % CCH);
    float4 y  = reinterpret_cast<const float4*>(Y)[i4];
    float4 xv = reinterpret_cast<const float4*>(x)[i4];
    uchar4 av = reinterpret_cast<const uchar4*>(ares)[i4];
    float2 s = st[o];
    float gg = g[o], bb = bet[o];
    float4 r;
    {
        float x1;
        x1 = xv.x + (float)av.x; r.x = x1 + (spike_f32(y.x, s, gg, bb) ? 1.0f : 0.0f);
        x1 = xv.y + (float)av.y; r.y = x1 + (spike_f32(y.y, s, gg, bb) ? 1.0f : 0.0f);
        x1 = xv.z + (float)av.z; r.z = x1 + (spike_f32(y.z, s, gg, bb) ? 1.0f : 0.0f);
        x1 = xv.w + (float)av.w; r.w = x1 + (spike_f32(y.w, s, gg, bb) ? 1.0f : 0.0f);
    }
    reinterpret_cast<float4*>(Out)[i4] = r;
}

extern "C" void kernel_launch(void* const* d_in, const int* in_sizes, int n_in,
                              void* d_out, int out_size, void* d_ws, size_t ws_size,
                              hipStream_t stream)
{
    const float* x         = (const float*)d_in[0];
    const float* q_w       = (const float*)d_in[1];
    const float* q_g       = (const float*)d_in[2];
    const float* q_b       = (const float*)d_in[3];
    const float* k_w       = (const float*)d_in[4];
    const float* k_g       = (const float*)d_in[5];
    const float* k_b       = (const float*)d_in[6];
    const float* v_w       = (const float*)d_in[7];
    const float* v_g       = (const float*)d_in[8];
    const float* v_b       = (const float*)d_in[9];
    const float* proj_w    = (const float*)d_in[10];
    const float* proj_bias = (const float*)d_in[11];
    const float* proj_g    = (const float*)d_in[12];
    const float* proj_b    = (const float*)d_in[13];
    const float* fc1_w     = (const float*)d_in[14];
    const float* fc1_bias  = (const float*)d_in[15];
    const float* fc1_g     = (const float*)d_in[16];
    const float* fc1_b     = (const float*)d_in[17];
    const float* fc2_w     = (const float*)d_in[18];
    const float* fc2_bias  = (const float*)d_in[19];
    const float* fc2_g     = (const float*)d_in[20];
    const float* fc2_b     = (const float*)d_in[21];
    float* out = (float*)d_out;

    char* ws = (char*)d_ws;
    const size_t MiB = 1ull << 20;
    if (ws_size < 115 * MiB) return;

    // ---- layout (115 MiB) ----
    float*    Af    = (float*)(ws);                  // 64 MiB: f32 GEMM out (up to 1024 ch for fc1 chunks)
    uint8_t*  ab    = (uint8_t*)(ws + 64 * MiB);     //  8 MiB: attention spikes [B,C,N]
    uint8_t*  ares  = (uint8_t*)(ws + 72 * MiB);     //  8 MiB: proj spikes, live to end
    uint8_t*  qb    = (uint8_t*)(ws + 80 * MiB);     //  8 MiB [B,H,N,D]
    uint8_t*  kb    = (uint8_t*)(ws + 88 * MiB);     //  8 MiB
    uint8_t*  vb    = (uint8_t*)(ws + 96 * MiB);     //  8 MiB
    uint8_t*  hb    = (uint8_t*)(ws + 80 * MiB);     // 32 MiB: fc1 spikes (overlays q/k/v after attn)
    float*    Mbuf  = (float*)(ws + 112 * MiB);      //  2 MiB
    float2*   stats = (float2*)(ws + 114 * MiB);     // 16 KiB

    dim3 thr256(256);
    // grids: 32o x 256n tiles
    dim3 g512(4, 16, 16);    // O=512  -> 1024 blocks (4 blocks/CU)
    dim3 g1024(4, 32, 16);   // O=1024 -> 2048 blocks

    // --- q, k, v ---
    const float* Wt[3] = {q_w, k_w, v_w};
    const float* Gt[3] = {q_g, k_g, v_g};
    const float* Bt[3] = {q_b, k_b, v_b};
    uint8_t*     Pt[3] = {qb, kb, vb};
    for (int tsr = 0; tsr < 3; ++tsr) {
        gemm_k<0><<<g512, thr256, 0, stream>>>(Wt[tsr], x, nullptr, nullptr, Af, 512, 512, 1024);
        bn_stats_np_k<<<dim3(512), dim3(64), 0, stream>>>(Af, 512, stats);
        spike_pack_k<<<dim3(16, 8, 16), thr256, 0, stream>>>(Af, stats, Gt[tsr], Bt[tsr], Pt[tsr]);
    }

    // --- attention (exact integers) ---
    ktv_k<<<dim3(128), thr256, 0, stream>>>(kb, vb, Mbuf);
    attn_spike_k<<<dim3(16, 8, 16), thr256, 0, stream>>>(qb, Mbuf, ab);

    // --- proj ---
    gemm_k<1><<<g512, thr256, 0, stream>>>(proj_w, nullptr, ab, proj_bias, Af, 512, 512, 1024);
    bn_stats_np_k<<<dim3(512), dim3(64), 0, stream>>>(Af, 512, stats);
    spike_store_k<<<dim3(8192), thr256, 0, stream>>>(Af, stats, proj_g, proj_b, ares, 512, 0, 512);

    // --- fc1 on x1 = f32(x + ares), 2 chunks of 1024 out-ch ---
    for (int ch = 0; ch < 2; ++ch) {
        gemm_k<2><<<g1024, thr256, 0, stream>>>(fc1_w + (size_t)ch * 1024 * 512, x, ares,
                                                fc1_bias + ch * 1024, Af, 1024, 512, 1024);
        bn_stats_np_k<<<dim3(1024), dim3(64), 0, stream>>>(Af, 1024, stats);
        spike_store_k<<<dim3(16384), thr256, 0, stream>>>(Af, stats, fc1_g + ch * 1024, fc1_b + ch * 1024,
                                                          hb, 1024, ch * 1024, 2048);
    }

    // --- fc2 + final residual ---
    gemm_k<1><<<g512, thr256, 0, stream>>>(fc2_w, nullptr, hb, fc2_bias, Af, 512, 2048, 1024);
    bn_stats_np_k<<<dim3(512), dim3(64), 0, stream>>>(Af, 512, stats);
    final_k<<<dim3(8192), thr256, 0, stream>>>(Af, stats, fc2_g, fc2_b, x, ares, out);
}

// Round 9
// 1502.477 us; speedup vs baseline: 1.5506x; 1.2117x over previous
//
#include <hip/hip_runtime.h>
#include <stdint.h>

#pragma clang fp contract(off)

#define BATCH 16
#define CCH   512
#define NLEN  1024
#define NH    8
#define DH    64

// ================= numpy-pairwise emulation (f32, no contraction) =================
__device__ float pw128(const float* __restrict__ x) {
    float r0=x[0],r1=x[1],r2=x[2],r3=x[3],r4=x[4],r5=x[5],r6=x[6],r7=x[7];
    for (int i = 8; i < 128; i += 8) {
        r0 += x[i+0]; r1 += x[i+1]; r2 += x[i+2]; r3 += x[i+3];
        r4 += x[i+4]; r5 += x[i+5]; r6 += x[i+6]; r7 += x[i+7];
    }
    return ((r0+r1)+(r2+r3))+((r4+r5)+(r6+r7));
}
__device__ float pw128_sqdev(const float* __restrict__ x, float m) {
    float r0,r1,r2,r3,r4,r5,r6,r7;
    {
        float d;
        d = x[0]-m; r0 = d*d;  d = x[1]-m; r1 = d*d;
        d = x[2]-m; r2 = d*d;  d = x[3]-m; r3 = d*d;
        d = x[4]-m; r4 = d*d;  d = x[5]-m; r5 = d*d;
        d = x[6]-m; r6 = d*d;  d = x[7]-m; r7 = d*d;
    }
    for (int i = 8; i < 128; i += 8) {
        float d;
        d = x[i+0]-m; r0 += d*d;  d = x[i+1]-m; r1 += d*d;
        d = x[i+2]-m; r2 += d*d;  d = x[i+3]-m; r3 += d*d;
        d = x[i+4]-m; r4 += d*d;  d = x[i+5]-m; r5 += d*d;
        d = x[i+6]-m; r6 += d*d;  d = x[i+7]-m; r7 += d*d;
    }
    return ((r0+r1)+(r2+r3))+((r4+r5)+(r6+r7));
}

// BN stats, numpy semantics (bit-exact): pairwise mean, two-pass var, CR f32 rsqrt.
__global__ __launch_bounds__(64) void bn_stats_np_k(const float* __restrict__ Y, int O,
                                                    float2* __restrict__ st)
{
    const int o = blockIdx.x;
    const int t = threadIdx.x;
    __shared__ float part[16];
    __shared__ float msh;
    if (t < 16) {
        const float* p = Y + ((size_t)t * O + o) * NLEN;
        float b0 = pw128(p), b1 = pw128(p+128), b2 = pw128(p+256), b3 = pw128(p+384);
        float b4 = pw128(p+512), b5 = pw128(p+640), b6 = pw128(p+768), b7 = pw128(p+896);
        part[t] = ((b0+b1)+(b2+b3))+((b4+b5)+(b6+b7));
    }
    __syncthreads();
    if (t == 0) {
        float s = part[0];
        for (int b = 1; b < 16; ++b) s += part[b];
        msh = s / 16384.0f;
    }
    __syncthreads();
    const float m = msh;
    if (t < 16) {
        const float* p = Y + ((size_t)t * O + o) * NLEN;
        float b0 = pw128_sqdev(p,     m), b1 = pw128_sqdev(p+128, m);
        float b2 = pw128_sqdev(p+256, m), b3 = pw128_sqdev(p+384, m);
        float b4 = pw128_sqdev(p+512, m), b5 = pw128_sqdev(p+640, m);
        float b6 = pw128_sqdev(p+768, m), b7 = pw128_sqdev(p+896, m);
        part[t] = ((b0+b1)+(b2+b3))+((b4+b5)+(b6+b7));
    }
    __syncthreads();
    if (t == 0) {
        float s = part[0];
        for (int b = 1; b < 16; ++b) s += part[b];
        float var = s / 16384.0f;
        float ve  = var + 1e-5f;
        float sq  = (float)sqrt((double)ve);    // correctly-rounded f32 sqrt
        float r   = (float)(1.0 / (double)sq);  // correctly-rounded f32 reciprocal
        st[o] = make_float2(m, r);
    }
}

// spike of bn output, f32 reference op order
__device__ inline bool spike_f32(float y, float2 s, float g, float b) {
    float t1 = y - s.x;
    float t2 = t1 * s.y;
    float t3 = t2 * g;
    float t4 = t3 + b;
    float u  = t4 / 2.0f - 1.0f;
    return u >= 0.0f;
}

// ================= Dense GEMM (r6 v2): 128x128 tile, 512 threads, BK=32 =================
// Bit-exactness: each output element is one thread's strict sequential ascending-c
// f32 FMA chain (matches np einsum); bias added once at the end.
// MODE 0: X = Xf (f32)   MODE 2: X = f32(Xf + Xs8)
template<int MODE>
__global__ __launch_bounds__(512, 2) void gemm_k(
    const float* __restrict__ W, const float* __restrict__ Xf, const uint8_t* __restrict__ Xs8,
    const float* __restrict__ bias, float* __restrict__ Y,
    int O, int Cin, int N)
{
    __shared__ float Ws[32][132];
    __shared__ float Xs[32][132];
    const int b = blockIdx.z;
    const size_t xbase = (size_t)b * Cin * N;
    float* Yb = Y + (size_t)b * O * N;
    const int o0 = blockIdx.y * 128;
    const int n0 = blockIdx.x * 128;
    const int t  = threadIdx.x;
    const int tx = t & 15;
    const int ty = t >> 4;

    const int wr = t >> 2;
    const int wk = (t & 3) << 3;
    const int xk = t >> 4;
    const int xc = (t & 15) << 3;

    float acc[4][8];
#pragma unroll
    for (int i = 0; i < 4; ++i)
#pragma unroll
        for (int j = 0; j < 8; ++j) acc[i][j] = 0.0f;

    float4 wA0, wA1;
    float  xr[8];

    auto loadG = [&](int k0) {
        const float* wp = W + (size_t)(o0 + wr) * Cin + k0 + wk;
        wA0 = *reinterpret_cast<const float4*>(wp);
        wA1 = *reinterpret_cast<const float4*>(wp + 4);
        size_t off = xbase + (size_t)(k0 + xk) * N + n0 + xc;
        if (MODE == 0) {
            float4 v0 = *reinterpret_cast<const float4*>(Xf + off);
            float4 v1 = *reinterpret_cast<const float4*>(Xf + off + 4);
            xr[0]=v0.x; xr[1]=v0.y; xr[2]=v0.z; xr[3]=v0.w;
            xr[4]=v1.x; xr[5]=v1.y; xr[6]=v1.z; xr[7]=v1.w;
        } else {
            float4 v0 = *reinterpret_cast<const float4*>(Xf + off);
            float4 v1 = *reinterpret_cast<const float4*>(Xf + off + 4);
            uchar4 u0 = *reinterpret_cast<const uchar4*>(Xs8 + off);
            uchar4 u1 = *reinterpret_cast<const uchar4*>(Xs8 + off + 4);
            xr[0]=v0.x+(float)u0.x; xr[1]=v0.y+(float)u0.y;
            xr[2]=v0.z+(float)u0.z; xr[3]=v0.w+(float)u0.w;
            xr[4]=v1.x+(float)u1.x; xr[5]=v1.y+(float)u1.y;
            xr[6]=v1.z+(float)u1.z; xr[7]=v1.w+(float)u1.w;
        }
    };
    auto stage = [&]() {
        Ws[wk+0][wr]=wA0.x; Ws[wk+1][wr]=wA0.y; Ws[wk+2][wr]=wA0.z; Ws[wk+3][wr]=wA0.w;
        Ws[wk+4][wr]=wA1.x; Ws[wk+5][wr]=wA1.y; Ws[wk+6][wr]=wA1.z; Ws[wk+7][wr]=wA1.w;
        *reinterpret_cast<float4*>(&Xs[xk][xc])     = make_float4(xr[0],xr[1],xr[2],xr[3]);
        *reinterpret_cast<float4*>(&Xs[xk][xc + 4]) = make_float4(xr[4],xr[5],xr[6],xr[7]);
    };

    loadG(0);
    stage();
    __syncthreads();
    for (int k0 = 0;;) {
        const int kn = k0 + 32;
        const bool more = kn < Cin;
        if (more) loadG(kn);
#pragma unroll
        for (int kk = 0; kk < 32; ++kk) {
            float4 a  = *reinterpret_cast<const float4*>(&Ws[kk][ty * 4]);
            float4 b0 = *reinterpret_cast<const float4*>(&Xs[kk][tx * 4]);
            float4 b1 = *reinterpret_cast<const float4*>(&Xs[kk][64 + tx * 4]);
            float av[4] = {a.x, a.y, a.z, a.w};
            float bv[8] = {b0.x, b0.y, b0.z, b0.w, b1.x, b1.y, b1.z, b1.w};
#pragma unroll
            for (int i = 0; i < 4; ++i)
#pragma unroll
                for (int j = 0; j < 8; ++j)
                    acc[i][j] = fmaf(av[i], bv[j], acc[i][j]);
        }
        if (!more) break;
        __syncthreads();
        stage();
        __syncthreads();
        k0 = kn;
    }
#pragma unroll
    for (int i = 0; i < 4; ++i) {
        const int o = o0 + ty * 4 + i;
        const float bb = bias ? bias[o] : 0.0f;
        float* yp = Yb + (size_t)o * N + n0;
        float4 r0, r1;
        r0.x = acc[i][0] + bb; r0.y = acc[i][1] + bb;
        r0.z = acc[i][2] + bb; r0.w = acc[i][3] + bb;
        r1.x = acc[i][4] + bb; r1.y = acc[i][5] + bb;
        r1.z = acc[i][6] + bb; r1.w = acc[i][7] + bb;
        *reinterpret_cast<float4*>(yp + tx * 4)      = r0;
        *reinterpret_cast<float4*>(yp + 64 + tx * 4) = r1;
    }
}

// ================= W transpose: Wt[k][o] = W[o][k] (bit-exact copy) =================
__global__ __launch_bounds__(256) void wt_k(const float* __restrict__ W, float* __restrict__ Wt,
                                            int O, int Cin)
{
    __shared__ float tile[32][33];
    const int k0 = blockIdx.x * 32, o0 = blockIdx.y * 32;
    const int tx = threadIdx.x & 31, ty = threadIdx.x >> 5;  // ty 0..7
#pragma unroll
    for (int j = 0; j < 4; ++j)
        tile[ty + 8*j][tx] = W[(size_t)(o0 + ty + 8*j) * Cin + k0 + tx];
    __syncthreads();
#pragma unroll
    for (int j = 0; j < 4; ++j)
        Wt[(size_t)(k0 + ty + 8*j) * O + o0 + tx] = tile[tx][ty + 8*j];
}

// ================= bit-pack spike columns: bits[b][n][k/64] (bit k%64) =================
__global__ __launch_bounds__(256) void col_bits_k(const uint8_t* __restrict__ S,
                                                  unsigned long long* __restrict__ bits, int Cin)
{
    // grid: (N/64, Cin/64, B)
    const int n0 = blockIdx.x * 64, kw = blockIdx.y, b = blockIdx.z;
    __shared__ uint8_t tile[64][64];   // [k][n], rows 64 B -> 16B-aligned
    const int t = threadIdx.x;
    const int r = t >> 2, cg = (t & 3) * 16;
    const uint8_t* src = S + ((size_t)b * Cin + kw * 64 + r) * NLEN + n0 + cg;
    *reinterpret_cast<uint4*>(&tile[r][cg]) = *reinterpret_cast<const uint4*>(src);
    __syncthreads();
    if (t < 64) {
        unsigned long long m = 0;
#pragma unroll
        for (int rr = 0; rr < 64; ++rr)
            m |= ((unsigned long long)(tile[rr][t] != 0)) << rr;
        bits[((size_t)b * NLEN + n0 + t) * (Cin >> 6) + kw] = m;
    }
}

// ================= sparse GEMM (binary X): one wave per (b,n) column, O=512 =================
// Bit-exact vs dense chain: fmaf(w,0,acc)=acc exactly; fmaf(w,1,acc)=IEEE add.
// Active k iterated ascending (words ascending, ctz within word) == sequential chain.
__global__ __launch_bounds__(256) void sparse_gemm_k(
    const float* __restrict__ Wt, const unsigned long long* __restrict__ bits,
    const float* __restrict__ bias, float* __restrict__ Y, int Cin)
{
    const int wid  = (blockIdx.x << 2) + (threadIdx.x >> 6);
    const int lane = threadIdx.x & 63;
    const int b = wid >> 10, n = wid & 1023;
    const int W64 = Cin >> 6;
    float acc[8];
#pragma unroll
    for (int i = 0; i < 8; ++i) acc[i] = 0.0f;
    const unsigned long long* bp = bits + ((size_t)b * NLEN + n) * W64;
    for (int w = 0; w < W64; ++w) {
        unsigned long long m = bp[w];
        while (m) {
            const int bit = __builtin_ctzll(m);
            m &= m - 1;
            const int k = (w << 6) + bit;
            const float* wr = Wt + ((size_t)k << 9) + lane * 8;  // O=512
            float4 w0 = *reinterpret_cast<const float4*>(wr);
            float4 w1 = *reinterpret_cast<const float4*>(wr + 4);
            acc[0] += w0.x; acc[1] += w0.y; acc[2] += w0.z; acc[3] += w0.w;
            acc[4] += w1.x; acc[5] += w1.y; acc[6] += w1.z; acc[7] += w1.w;
        }
    }
    const float* bq = bias + lane * 8;
    float4 b0 = *reinterpret_cast<const float4*>(bq);
    float4 b1 = *reinterpret_cast<const float4*>(bq + 4);
    float bi[8] = {b0.x, b0.y, b0.z, b0.w, b1.x, b1.y, b1.z, b1.w};
    float* yp = Y + ((size_t)b * 512 + lane * 8) * NLEN + n;
#pragma unroll
    for (int i = 0; i < 8; ++i)
        yp[(size_t)i * NLEN] = acc[i] + bi[i];
}

// ================= spike + transpose to [B,H,N,D] u8 =================
__global__ __launch_bounds__(256) void spike_pack_k(
    const float* __restrict__ Y, const float2* __restrict__ st,
    const float* __restrict__ g, const float* __restrict__ bet,
    uint8_t* __restrict__ out)
{
    const int nt = blockIdx.x, h = blockIdx.y, b = blockIdx.z;
    __shared__ uint8_t tile[64][68];
    const int t = threadIdx.x;
    {
        const int i = t & 63, dq = t >> 6;
#pragma unroll
        for (int p = 0; p < 16; ++p) {
            int d = dq * 16 + p;
            int c = h * 64 + d;
            float y = Y[((size_t)b * CCH + c) * NLEN + nt * 64 + i];
            tile[d][i] = spike_f32(y, st[c], g[c], bet[c]) ? 1 : 0;
        }
    }
    __syncthreads();
    {
        const int d = t & 63, iq = t >> 6;
#pragma unroll
        for (int p = 0; p < 16; ++p) {
            int i = iq * 16 + p;
            out[((size_t)(b * NH + h) * NLEN + nt * 64 + i) * DH + d] = tile[d][i];
        }
    }
}

// ================= M = K^T V  [B*H, 64, 64]  (exact integers) =================
__global__ __launch_bounds__(256) void ktv_k(const uint8_t* __restrict__ Kb, const uint8_t* __restrict__ Vb,
                                             float* __restrict__ M)
{
    const int bh = blockIdx.x;
    const uint8_t* kp = Kb + (size_t)bh * NLEN * DH;
    const uint8_t* vp = Vb + (size_t)bh * NLEN * DH;
    __shared__ float ks[64][68];
    __shared__ float vs[64][68];
    const int t = threadIdx.x;
    const int d2 = t & 63, g4 = t >> 6;
    float acc[16];
#pragma unroll
    for (int j = 0; j < 16; ++j) acc[j] = 0.f;

    for (int nc = 0; nc < NLEN; nc += 64) {
#pragma unroll
        for (int p = 0; p < 16; ++p) {
            int idx = t + p * 256;
            int r = idx >> 6, d = idx & 63;
            ks[r][d] = (float)kp[(size_t)(nc + r) * DH + d];
            vs[r][d] = (float)vp[(size_t)(nc + r) * DH + d];
        }
        __syncthreads();
        for (int n = 0; n < 64; ++n) {
            float vv = vs[n][d2];
#pragma unroll
            for (int j = 0; j < 16; ++j)
                acc[j] += ks[n][g4 * 16 + j] * vv;
        }
        __syncthreads();
    }
#pragma unroll
    for (int j = 0; j < 16; ++j)
        M[(size_t)bh * 4096 + (size_t)(g4 * 16 + j) * 64 + d2] = acc[j];
}

// ================= attn = Q @ M, integer spike attn>=8, write [B,C,N] u8 =================
__global__ __launch_bounds__(256) void attn_spike_k(const uint8_t* __restrict__ Qb, const float* __restrict__ M,
                                                    uint8_t* __restrict__ A)
{
    const int nt = blockIdx.x, h = blockIdx.y, b = blockIdx.z;
    const int bh = b * NH + h;
    __shared__ float Ms[64][68];
    __shared__ float qs[64][65];
    const int t = threadIdx.x;
#pragma unroll
    for (int p = 0; p < 16; ++p) {
        int idx = t + p * 256;
        int r = idx >> 6, c = idx & 63;
        Ms[r][c] = M[(size_t)bh * 4096 + idx];
        qs[c][r] = (float)Qb[((size_t)bh * NLEN + nt * 64 + r) * DH + c];
    }
    __syncthreads();
    const int n = t & 63, dg = t >> 6;
    float acc[16];
#pragma unroll
    for (int j = 0; j < 16; ++j) acc[j] = 0.f;
    for (int d1 = 0; d1 < 64; ++d1) {
        float qv = qs[d1][n];
#pragma unroll
        for (int j = 0; j < 16; ++j)
            acc[j] += qv * Ms[d1][dg * 16 + j];
    }
#pragma unroll
    for (int j = 0; j < 16; ++j) {
        int d = dg * 16 + j;
        A[((size_t)b * CCH + h * 64 + d) * NLEN + nt * 64 + n] = (acc[j] >= 8.0f) ? 1 : 0;
    }
}

// ================= spike -> u8 store at channel offset =================
__global__ __launch_bounds__(256) void spike_store_k(
    const float* __restrict__ Y, const float2* __restrict__ st,
    const float* __restrict__ g, const float* __restrict__ bet,
    uint8_t* __restrict__ H, int Oc, int o_off, int Otot)
{
    size_t i4 = (size_t)blockIdx.x * 256 + threadIdx.x;
    size_t total = (size_t)BATCH * Oc * (NLEN / 4);
    if (i4 >= total) return;
    int n4 = (int)(i4 & 255);
    int o  = (int)((i4 >> 8) % Oc);
    int b  = (int)(i4 / ((size_t)256 * Oc));
    float4 y = reinterpret_cast<const float4*>(Y)[i4];
    float2 s = st[o];
    float gg = g[o], bb = bet[o];
    uchar4 r;
    r.x = spike_f32(y.x, s, gg, bb) ? 1 : 0;
    r.y = spike_f32(y.y, s, gg, bb) ? 1 : 0;
    r.z = spike_f32(y.z, s, gg, bb) ? 1 : 0;
    r.w = spike_f32(y.w, s, gg, bb) ? 1 : 0;
    *reinterpret_cast<uchar4*>(H + ((size_t)(b * Otot + o_off + o)) * NLEN + n4 * 4) = r;
}

// ================= out = (x + ares) + spike(bn(Y)) in np f32 order =================
__global__ __launch_bounds__(256) void final_k(
    const float* __restrict__ Y, const float2* __restrict__ st,
    const float* __restrict__ g, const float* __restrict__ bet,
    const float* __restrict__ x, const uint8_t* __restrict__ ares,
    float* __restrict__ Out)
{
    size_t i4 = (size_t)blockIdx.x * 256 + threadIdx.x;
    size_t total = (size_t)BATCH * CCH * (NLEN / 4);
    if (i4 >= total) return;
    int o = (int)((i4 >> 8) % CCH);
    float4 y  = reinterpret_cast<const float4*>(Y)[i4];
    float4 xv = reinterpret_cast<const float4*>(x)[i4];
    uchar4 av = reinterpret_cast<const uchar4*>(ares)[i4];
    float2 s = st[o];
    float gg = g[o], bb = bet[o];
    float4 r;
    {
        float x1;
        x1 = xv.x + (float)av.x; r.x = x1 + (spike_f32(y.x, s, gg, bb) ? 1.0f : 0.0f);
        x1 = xv.y + (float)av.y; r.y = x1 + (spike_f32(y.y, s, gg, bb) ? 1.0f : 0.0f);
        x1 = xv.z + (float)av.z; r.z = x1 + (spike_f32(y.z, s, gg, bb) ? 1.0f : 0.0f);
        x1 = xv.w + (float)av.w; r.w = x1 + (spike_f32(y.w, s, gg, bb) ? 1.0f : 0.0f);
    }
    reinterpret_cast<float4*>(Out)[i4] = r;
}

extern "C" void kernel_launch(void* const* d_in, const int* in_sizes, int n_in,
                              void* d_out, int out_size, void* d_ws, size_t ws_size,
                              hipStream_t stream)
{
    const float* x         = (const float*)d_in[0];
    const float* q_w       = (const float*)d_in[1];
    const float* q_g       = (const float*)d_in[2];
    const float* q_b       = (const float*)d_in[3];
    const float* k_w       = (const float*)d_in[4];
    const float* k_g       = (const float*)d_in[5];
    const float* k_b       = (const float*)d_in[6];
    const float* v_w       = (const float*)d_in[7];
    const float* v_g       = (const float*)d_in[8];
    const float* v_b       = (const float*)d_in[9];
    const float* proj_w    = (const float*)d_in[10];
    const float* proj_bias = (const float*)d_in[11];
    const float* proj_g    = (const float*)d_in[12];
    const float* proj_b    = (const float*)d_in[13];
    const float* fc1_w     = (const float*)d_in[14];
    const float* fc1_bias  = (const float*)d_in[15];
    const float* fc1_g     = (const float*)d_in[16];
    const float* fc1_b     = (const float*)d_in[17];
    const float* fc2_w     = (const float*)d_in[18];
    const float* fc2_bias  = (const float*)d_in[19];
    const float* fc2_g     = (const float*)d_in[20];
    const float* fc2_b     = (const float*)d_in[21];
    float* out = (float*)d_out;

    char* ws = (char*)d_ws;
    const size_t MiB = 1ull << 20;
    if (ws_size < 124 * MiB) return;

    // ---- layout (124 MiB) ----
    float*    Af    = (float*)(ws);                  // 64 MiB: f32 GEMM out
    uint8_t*  ab    = (uint8_t*)(ws + 64 * MiB);     //  8 MiB: attention spikes [B,C,N]
    uint8_t*  ares  = (uint8_t*)(ws + 72 * MiB);     //  8 MiB: proj spikes, live to end
    uint8_t*  qb    = (uint8_t*)(ws + 80 * MiB);     //  8 MiB [B,H,N,D]
    uint8_t*  kb    = (uint8_t*)(ws + 88 * MiB);     //  8 MiB
    uint8_t*  vb    = (uint8_t*)(ws + 96 * MiB);     //  8 MiB
    uint8_t*  hb    = (uint8_t*)(ws + 80 * MiB);     // 32 MiB: fc1 spikes (overlays q/k/v after attn)
    float*    Mbuf  = (float*)(ws + 112 * MiB);      //  2 MiB
    float2*   stats = (float2*)(ws + 114 * MiB);     // 16 KiB
    float*    Wt    = (float*)(ws + 115 * MiB);      //  4 MiB (max 2048x512 f32)
    unsigned long long* bits = (unsigned long long*)(ws + 119 * MiB);  // 4 MiB (max B*N*2048 bits)

    dim3 thr256(256), thr512(512);

    // --- q, k, v (dense) ---
    const float* Wts[3] = {q_w, k_w, v_w};
    const float* Gt[3]  = {q_g, k_g, v_g};
    const float* Bt[3]  = {q_b, k_b, v_b};
    uint8_t*     Pt[3]  = {qb, kb, vb};
    for (int tsr = 0; tsr < 3; ++tsr) {
        gemm_k<0><<<dim3(8, 4, 16), thr512, 0, stream>>>(Wts[tsr], x, nullptr, nullptr, Af, 512, 512, 1024);
        bn_stats_np_k<<<dim3(512), dim3(64), 0, stream>>>(Af, 512, stats);
        spike_pack_k<<<dim3(16, 8, 16), thr256, 0, stream>>>(Af, stats, Gt[tsr], Bt[tsr], Pt[tsr]);
    }

    // --- attention (exact integers) ---
    ktv_k<<<dim3(128), thr256, 0, stream>>>(kb, vb, Mbuf);
    attn_spike_k<<<dim3(16, 8, 16), thr256, 0, stream>>>(qb, Mbuf, ab);

    // --- proj (sparse binary-input GEMM) ---
    wt_k<<<dim3(16, 16), thr256, 0, stream>>>(proj_w, Wt, 512, 512);
    col_bits_k<<<dim3(16, 8, 16), thr256, 0, stream>>>(ab, bits, 512);
    sparse_gemm_k<<<dim3(4096), thr256, 0, stream>>>(Wt, bits, proj_bias, Af, 512);
    bn_stats_np_k<<<dim3(512), dim3(64), 0, stream>>>(Af, 512, stats);
    spike_store_k<<<dim3(8192), thr256, 0, stream>>>(Af, stats, proj_g, proj_b, ares, 512, 0, 512);

    // --- fc1 on x1 = f32(x + ares), dense, 2 chunks of 1024 out-ch ---
    for (int ch = 0; ch < 2; ++ch) {
        gemm_k<2><<<dim3(8, 8, 16), thr512, 0, stream>>>(fc1_w + (size_t)ch * 1024 * 512, x, ares,
                                                         fc1_bias + ch * 1024, Af, 1024, 512, 1024);
        bn_stats_np_k<<<dim3(1024), dim3(64), 0, stream>>>(Af, 1024, stats);
        spike_store_k<<<dim3(16384), thr256, 0, stream>>>(Af, stats, fc1_g + ch * 1024, fc1_b + ch * 1024,
                                                          hb, 1024, ch * 1024, 2048);
    }

    // --- fc2 (sparse binary-input GEMM) + final residual ---
    wt_k<<<dim3(64, 16), thr256, 0, stream>>>(fc2_w, Wt, 512, 2048);
    col_bits_k<<<dim3(16, 32, 16), thr256, 0, stream>>>(hb, bits, 2048);
    sparse_gemm_k<<<dim3(4096), thr256, 0, stream>>>(Wt, bits, fc2_bias, Af, 2048);
    bn_stats_np_k<<<dim3(512), dim3(64), 0, stream>>>(Af, 512, stats);
    final_k<<<dim3(8192), thr256, 0, stream>>>(Af, stats, fc2_g, fc2_b, x, ares, out);
}